// Round 10
// baseline (298.714 us; speedup 1.0000x reference)
//
#include <hip/hip_runtime.h>
#include <hip/hip_fp16.h>

#define N_NODES 100000
#define N_EDGES 1250000
#define C 64
#define NPB 128          // nodes per bucket (dst >> 7)
#define NB 782           // ceil(100000/128)
#define CAP 2048         // bucket capacity (mean 1598, sigma ~40 -> 11 sigma headroom)
#define P1_CHUNKQ 2048   // int4-quads per partition block = 8192 edges
#define P1_BLOCKS 153    // ceil(312500 / 2048)
#define NQ (N_EDGES / 4) // 312500

typedef int vint4 __attribute__((ext_vector_type(4)));

// ---------------- pass 1: partition edges into 128-node dst-buckets ----------------
// Edges read ONCE into registers (32/thread). Per-wave LDS histogram replicas
// (no cross-wave same-address serialization in phase A); one global atomic per
// (block,bucket) reservation; run-grouped packed writes ((src<<7)|dst_local).
__global__ __launch_bounds__(256) void partition_kernel(
        const int* __restrict__ src, const int* __restrict__ dst,
        int* __restrict__ gcnt, unsigned int* __restrict__ packed) {
    __shared__ int s_hist[4][NB];  // 12.5 KB
    __shared__ int s_cur[NB];      // 3.1 KB
    const int t = threadIdx.x;
    const int w = t >> 6;
    for (int i = t; i < 4 * NB; i += 256) ((int*)s_hist)[i] = 0;
    __syncthreads();

    const int qbase = blockIdx.x * P1_CHUNKQ;
    const vint4* d4 = (const vint4*)dst;
    const vint4* s4 = (const vint4*)src;

    vint4 dreg[8], sreg[8];
    bool val[8];
#pragma unroll
    for (int k = 0; k < 8; ++k) {
        int q = qbase + k * 256 + t;
        val[k] = q < NQ;
        if (val[k]) {
            dreg[k] = __builtin_nontemporal_load(&d4[q]);
            sreg[k] = __builtin_nontemporal_load(&s4[q]);
        }
    }

    // phase A: per-wave histogram
#pragma unroll
    for (int k = 0; k < 8; ++k) {
        if (val[k]) {
            atomicAdd(&s_hist[w][dreg[k].x >> 7], 1);
            atomicAdd(&s_hist[w][dreg[k].y >> 7], 1);
            atomicAdd(&s_hist[w][dreg[k].z >> 7], 1);
            atomicAdd(&s_hist[w][dreg[k].w >> 7], 1);
        }
    }
    __syncthreads();

    // phase B: merge replicas, reserve global runs
    for (int b = t; b < NB; b += 256) {
        int tot = s_hist[0][b] + s_hist[1][b] + s_hist[2][b] + s_hist[3][b];
        s_cur[b] = (tot > 0) ? (b * CAP + atomicAdd(&gcnt[b], tot)) : 0;
    }
    __syncthreads();

    // phase C: scatter from registers via shared cursors
#pragma unroll
    for (int k = 0; k < 8; ++k) {
        if (val[k]) {
            int bb, pos;
            bb = dreg[k].x >> 7; pos = atomicAdd(&s_cur[bb], 1);
            if (pos < (bb + 1) * CAP) packed[pos] = ((unsigned)sreg[k].x << 7) | (unsigned)(dreg[k].x & 127);
            bb = dreg[k].y >> 7; pos = atomicAdd(&s_cur[bb], 1);
            if (pos < (bb + 1) * CAP) packed[pos] = ((unsigned)sreg[k].y << 7) | (unsigned)(dreg[k].y & 127);
            bb = dreg[k].z >> 7; pos = atomicAdd(&s_cur[bb], 1);
            if (pos < (bb + 1) * CAP) packed[pos] = ((unsigned)sreg[k].z << 7) | (unsigned)(dreg[k].z & 127);
            bb = dreg[k].w >> 7; pos = atomicAdd(&s_cur[bb], 1);
            if (pos < (bb + 1) * CAP) packed[pos] = ((unsigned)sreg[k].w << 7) | (unsigned)(dreg[k].w & 127);
        }
    }
}

// ---------------- pass 2: per-bucket counting sort -> CSR (prefix inline) ----------------
__global__ __launch_bounds__(256) void sort_kernel(
        const unsigned int* __restrict__ packed,
        const int* __restrict__ gcnt,
        int* __restrict__ offsets, int* __restrict__ sorted_src) {
    __shared__ int s_part[256];
    __shared__ unsigned int s_e[CAP];  // 8 KB
    __shared__ int s_hist[NPB];
    __shared__ int s_excl[NPB];
    const int b = blockIdx.x;
    const int t = threadIdx.x;

    // inline exclusive prefix: base = sum gcnt[0..b-1] (L2-hot, ~3 KB)
    int psum = 0;
    for (int i = t; i < b; i += 256) psum += gcnt[i];
    s_part[t] = psum;
    __syncthreads();
    for (int off = 128; off > 0; off >>= 1) {
        if (t < off) s_part[t] += s_part[t + off];
        __syncthreads();
    }
    const int base = s_part[0];
    const int nb = min(gcnt[b], CAP);

    for (int i = t; i < NPB; i += 256) s_hist[i] = 0;
    __syncthreads();
    for (int i = t; i < nb; i += 256) {
        unsigned int u = packed[(size_t)b * CAP + i];
        s_e[i] = u;
        atomicAdd(&s_hist[u & 127u], 1);
    }
    __syncthreads();
    if (t < NPB) s_excl[t] = s_hist[t];
    __syncthreads();
    for (int off = 1; off < NPB; off <<= 1) {
        int v = (t < NPB && t >= off) ? s_excl[t - off] : 0;
        __syncthreads();
        if (t < NPB) s_excl[t] += v;
        __syncthreads();
    }
    if (t < NPB) {
        int excl = s_excl[t] - s_hist[t];
        s_hist[t] = excl;  // becomes cursor
        int node = b * NPB + t;
        if (node < N_NODES) offsets[node] = base + excl;
    }
    __syncthreads();
    for (int i = t; i < nb; i += 256) {
        unsigned int u = s_e[i];
        int lp = atomicAdd(&s_hist[u & 127u], 1);
        sorted_src[base + lp] = (int)(u >> 7);
    }
    if (b == NB - 1 && t == 0) offsets[N_NODES] = N_EDGES;
}

// ---------------- dense: z = x @ W_l (fp16), r = x @ W_r + b (fp16) ----------------
// Register-tiled fp32 GEMM; input templated (fp32 layer 0, fp16 layer 1).
template <typename XT>
__global__ __launch_bounds__(256) void dense_kernel(
        const XT* __restrict__ x,
        const float* __restrict__ wl, const float* __restrict__ wr,
        const float* __restrict__ bl,
        __half* __restrict__ z, __half* __restrict__ r, int n_nodes) {
    __shared__ float s_w[C][2 * C];
    __shared__ float s_x[64][C + 1];

    const int t = threadIdx.x;
    const int base = blockIdx.x * 64;

    for (int i = t; i < C * C; i += 256) {
        int k = i >> 6, c = i & 63;
        s_w[k][c] = wl[i];
        s_w[k][64 + c] = wr[i];
    }
    if constexpr (sizeof(XT) == 4) {
        for (int i = t; i < 1024; i += 256) {
            int n = i >> 4;
            int kq = i & 15;
            float4 v = make_float4(0.f, 0.f, 0.f, 0.f);
            if (base + n < n_nodes) v = ((const float4*)x)[((size_t)(base + n) << 4) + kq];
            s_x[n][kq * 4 + 0] = v.x;
            s_x[n][kq * 4 + 1] = v.y;
            s_x[n][kq * 4 + 2] = v.z;
            s_x[n][kq * 4 + 3] = v.w;
        }
    } else {
        for (int i = t; i < 2048; i += 256) {
            int n = i >> 5;
            int c2 = i & 31;
            float2 f = make_float2(0.f, 0.f);
            if (base + n < n_nodes)
                f = __half22float2(((const __half2*)x)[(size_t)(base + n) * 32 + c2]);
            s_x[n][2 * c2 + 0] = f.x;
            s_x[n][2 * c2 + 1] = f.y;
        }
    }
    __syncthreads();

    const int lane = t & 63;
    const int wv = t >> 6;
    const int cg = lane & 15;
    const int q = lane >> 4;
    const int n0 = wv * 16 + 4 * q;

    float4 bv = ((const float4*)bl)[cg];
    float accz[4][4];
    float accr[4][4];
#pragma unroll
    for (int i = 0; i < 4; ++i) {
        accz[i][0] = accz[i][1] = accz[i][2] = accz[i][3] = 0.f;
        accr[i][0] = bv.x; accr[i][1] = bv.y; accr[i][2] = bv.z; accr[i][3] = bv.w;
    }

#pragma unroll 8
    for (int k = 0; k < C; ++k) {
        float4 wlv = *(const float4*)&s_w[k][4 * cg];
        float4 wrv = *(const float4*)&s_w[k][64 + 4 * cg];
        float xk[4];
#pragma unroll
        for (int i = 0; i < 4; ++i) xk[i] = s_x[n0 + i][k];
#pragma unroll
        for (int i = 0; i < 4; ++i) {
            accz[i][0] += xk[i] * wlv.x;
            accz[i][1] += xk[i] * wlv.y;
            accz[i][2] += xk[i] * wlv.z;
            accz[i][3] += xk[i] * wlv.w;
            accr[i][0] += xk[i] * wrv.x;
            accr[i][1] += xk[i] * wrv.y;
            accr[i][2] += xk[i] * wrv.z;
            accr[i][3] += xk[i] * wrv.w;
        }
    }

#pragma unroll
    for (int i = 0; i < 4; ++i) {
        size_t gn = (size_t)base + n0 + i;
        if (gn < (size_t)n_nodes) {
            ((__half2*)z)[gn * 32 + 2 * cg + 0] = __float22half2_rn(make_float2(accz[i][0], accz[i][1]));
            ((__half2*)z)[gn * 32 + 2 * cg + 1] = __float22half2_rn(make_float2(accz[i][2], accz[i][3]));
            ((__half2*)r)[gn * 32 + 2 * cg + 0] = __float22half2_rn(make_float2(accr[i][0], accr[i][1]));
            ((__half2*)r)[gn * 32 + 2 * cg + 1] = __float22half2_rn(make_float2(accr[i][2], accr[i][3]));
        }
    }
}

// ---------------- gather: h = PReLU( mean_j z[nbr_j] + r ) ----------------
// Wave per node, lane = channel, 8 fp16 rows in flight; clamp-free main loop.
// Output templated: fp16 (layer 0, feeds dense) / fp32 (layer 1, d_out).
template <typename OT>
__global__ __launch_bounds__(256) void gather_kernel(
        const __half* __restrict__ z,
        const __half* __restrict__ r,
        const int* __restrict__ offsets,
        const int* __restrict__ sorted_src,
        const float* __restrict__ a,
        OT* __restrict__ out) {
    const int lane = threadIdx.x & 63;
    const int node = (blockIdx.x << 2) + (threadIdx.x >> 6);

    const int beg = offsets[node];
    const int deg = offsets[node + 1] - beg;
    const int deg8 = deg & ~7;

    float acc = 0.0f;
    int j = 0;
    for (; j < deg8; j += 8) {
        int s0 = sorted_src[beg + j + 0];
        int s1 = sorted_src[beg + j + 1];
        int s2 = sorted_src[beg + j + 2];
        int s3 = sorted_src[beg + j + 3];
        int s4 = sorted_src[beg + j + 4];
        int s5 = sorted_src[beg + j + 5];
        int s6 = sorted_src[beg + j + 6];
        int s7 = sorted_src[beg + j + 7];
        float v0 = __half2float(z[(size_t)s0 * C + lane]);
        float v1 = __half2float(z[(size_t)s1 * C + lane]);
        float v2 = __half2float(z[(size_t)s2 * C + lane]);
        float v3 = __half2float(z[(size_t)s3 * C + lane]);
        float v4 = __half2float(z[(size_t)s4 * C + lane]);
        float v5 = __half2float(z[(size_t)s5 * C + lane]);
        float v6 = __half2float(z[(size_t)s6 * C + lane]);
        float v7 = __half2float(z[(size_t)s7 * C + lane]);
        acc += ((v0 + v1) + (v2 + v3)) + ((v4 + v5) + (v6 + v7));
    }
    for (; j < deg; ++j)
        acc += __half2float(z[(size_t)sorted_src[beg + j] * C + lane]);

    float rv = __half2float(r[(size_t)node * C + lane]);
    float h = acc / (float)max(deg, 1) + rv;
    float av = a[lane];
    float o = h >= 0.0f ? h : av * h;
    if constexpr (sizeof(OT) == 2)
        out[(size_t)node * C + lane] = __float2half(o);
    else
        out[(size_t)node * C + lane] = o;
}

extern "C" void kernel_launch(void* const* d_in, const int* in_sizes, int n_in,
                              void* d_out, int out_size, void* d_ws, size_t ws_size,
                              hipStream_t stream) {
    const float* x    = (const float*)d_in[0];
    const int*   ei   = (const int*)d_in[1];
    const float* w_l0 = (const float*)d_in[2];
    const float* b_l0 = (const float*)d_in[3];
    const float* w_r0 = (const float*)d_in[4];
    const float* a0   = (const float*)d_in[5];
    const float* w_l1 = (const float*)d_in[6];
    const float* b_l1 = (const float*)d_in[7];
    const float* w_r1 = (const float*)d_in[8];
    const float* a1   = (const float*)d_in[9];
    float* out = (float*)d_out;

    const int* src = ei;            // edge_index[0, :]
    const int* dst = ei + N_EDGES;  // edge_index[1, :]

    // ws: gcnt[1024] | offsets[N+1] | packed[NB*CAP] | sorted_src[E] | Z | R | H (all fp16 N*C)
    int* gcnt            = (int*)d_ws;
    int* offsets         = gcnt + 1024;
    unsigned int* packed = (unsigned int*)(offsets + (N_NODES + 1));
    int* sorted_src      = (int*)(packed + (size_t)NB * CAP);
    __half* Z            = (__half*)(sorted_src + N_EDGES);
    __half* R            = Z + (size_t)N_NODES * C;
    __half* H            = R + (size_t)N_NODES * C;

    hipMemsetAsync(gcnt, 0, 1024 * sizeof(int), stream);

    const int dblocks = (N_NODES + 63) / 64;
    const int nblocks = N_NODES / 4;  // exact

    partition_kernel<<<P1_BLOCKS, 256, 0, stream>>>(src, dst, gcnt, packed);
    sort_kernel<<<NB, 256, 0, stream>>>(packed, gcnt, offsets, sorted_src);

    // Layer 0: dense fp32->fp16, gather -> H (fp16)
    dense_kernel<float><<<dblocks, 256, 0, stream>>>(x, w_l0, w_r0, b_l0, Z, R, N_NODES);
    gather_kernel<__half><<<nblocks, 256, 0, stream>>>(Z, R, offsets, sorted_src, a0, H);

    // Layer 1: dense fp16->fp16, gather -> d_out (fp32)
    dense_kernel<__half><<<dblocks, 256, 0, stream>>>(H, w_l1, w_r1, b_l1, Z, R, N_NODES);
    gather_kernel<float><<<nblocks, 256, 0, stream>>>(Z, R, offsets, sorted_src, a1, out);
}

// Round 11
// 267.565 us; speedup vs baseline: 1.1164x; 1.1164x over previous
//
#include <hip/hip_runtime.h>
#include <hip/hip_fp16.h>

#define N_NODES 100000
#define N_EDGES 1250000
#define C 64
#define NPB 128          // nodes per bucket (dst >> 7)
#define NB 782           // ceil(100000/128)
#define CAP 2048         // bucket capacity (mean 1598, sigma ~40 -> 11 sigma headroom)
#define P1_CHUNKQ 2048   // int4-quads per partition block = 8192 edges
#define P1_BLOCKS 153    // ceil(312500 / 2048)
#define NQ (N_EDGES / 4) // 312500

typedef int vint4 __attribute__((ext_vector_type(4)));

// ---------------- pass 1: partition edges into 128-node dst-buckets ----------------
__global__ __launch_bounds__(256) void partition_kernel(
        const int* __restrict__ src, const int* __restrict__ dst,
        int* __restrict__ gcnt, unsigned int* __restrict__ packed) {
    __shared__ int s_hist[4][NB];  // 12.5 KB
    __shared__ int s_cur[NB];      // 3.1 KB
    const int t = threadIdx.x;
    const int w = t >> 6;
    for (int i = t; i < 4 * NB; i += 256) ((int*)s_hist)[i] = 0;
    __syncthreads();

    const int qbase = blockIdx.x * P1_CHUNKQ;
    const vint4* d4 = (const vint4*)dst;
    const vint4* s4 = (const vint4*)src;

    vint4 dreg[8], sreg[8];
    bool val[8];
#pragma unroll
    for (int k = 0; k < 8; ++k) {
        int q = qbase + k * 256 + t;
        val[k] = q < NQ;
        if (val[k]) {
            dreg[k] = __builtin_nontemporal_load(&d4[q]);
            sreg[k] = __builtin_nontemporal_load(&s4[q]);
        }
    }

#pragma unroll
    for (int k = 0; k < 8; ++k) {
        if (val[k]) {
            atomicAdd(&s_hist[w][dreg[k].x >> 7], 1);
            atomicAdd(&s_hist[w][dreg[k].y >> 7], 1);
            atomicAdd(&s_hist[w][dreg[k].z >> 7], 1);
            atomicAdd(&s_hist[w][dreg[k].w >> 7], 1);
        }
    }
    __syncthreads();

    for (int b = t; b < NB; b += 256) {
        int tot = s_hist[0][b] + s_hist[1][b] + s_hist[2][b] + s_hist[3][b];
        s_cur[b] = (tot > 0) ? (b * CAP + atomicAdd(&gcnt[b], tot)) : 0;
    }
    __syncthreads();

#pragma unroll
    for (int k = 0; k < 8; ++k) {
        if (val[k]) {
            int bb, pos;
            bb = dreg[k].x >> 7; pos = atomicAdd(&s_cur[bb], 1);
            if (pos < (bb + 1) * CAP) packed[pos] = ((unsigned)sreg[k].x << 7) | (unsigned)(dreg[k].x & 127);
            bb = dreg[k].y >> 7; pos = atomicAdd(&s_cur[bb], 1);
            if (pos < (bb + 1) * CAP) packed[pos] = ((unsigned)sreg[k].y << 7) | (unsigned)(dreg[k].y & 127);
            bb = dreg[k].z >> 7; pos = atomicAdd(&s_cur[bb], 1);
            if (pos < (bb + 1) * CAP) packed[pos] = ((unsigned)sreg[k].z << 7) | (unsigned)(dreg[k].z & 127);
            bb = dreg[k].w >> 7; pos = atomicAdd(&s_cur[bb], 1);
            if (pos < (bb + 1) * CAP) packed[pos] = ((unsigned)sreg[k].w << 7) | (unsigned)(dreg[k].w & 127);
        }
    }
}

// ---------------- pass 2: per-bucket counting sort -> CSR (prefix inline) ----------------
__global__ __launch_bounds__(256) void sort_kernel(
        const unsigned int* __restrict__ packed,
        const int* __restrict__ gcnt,
        int* __restrict__ offsets, int* __restrict__ sorted_src) {
    __shared__ int s_part[256];
    __shared__ unsigned int s_e[CAP];  // 8 KB
    __shared__ int s_hist[NPB];
    __shared__ int s_excl[NPB];
    const int b = blockIdx.x;
    const int t = threadIdx.x;

    // inline exclusive prefix over L2-hot gcnt[0..b-1]
    int psum = 0;
    for (int i = t; i < b; i += 256) psum += gcnt[i];
    s_part[t] = psum;
    __syncthreads();
    for (int off = 128; off > 0; off >>= 1) {
        if (t < off) s_part[t] += s_part[t + off];
        __syncthreads();
    }
    const int base = s_part[0];
    const int nb = min(gcnt[b], CAP);

    for (int i = t; i < NPB; i += 256) s_hist[i] = 0;
    __syncthreads();
    // 4-wide NT reads of the bucket's packed run
    const vint4* p4 = (const vint4*)(packed + (size_t)b * CAP);
    for (int i4 = t; i4 * 4 < nb; i4 += 256) {
        vint4 u4 = __builtin_nontemporal_load(&p4[i4]);
        int i = i4 * 4;
        unsigned int u;
        u = (unsigned)u4.x; if (i + 0 < nb) { s_e[i + 0] = u; atomicAdd(&s_hist[u & 127u], 1); }
        u = (unsigned)u4.y; if (i + 1 < nb) { s_e[i + 1] = u; atomicAdd(&s_hist[u & 127u], 1); }
        u = (unsigned)u4.z; if (i + 2 < nb) { s_e[i + 2] = u; atomicAdd(&s_hist[u & 127u], 1); }
        u = (unsigned)u4.w; if (i + 3 < nb) { s_e[i + 3] = u; atomicAdd(&s_hist[u & 127u], 1); }
    }
    __syncthreads();
    if (t < NPB) s_excl[t] = s_hist[t];
    __syncthreads();
    for (int off = 1; off < NPB; off <<= 1) {
        int v = (t < NPB && t >= off) ? s_excl[t - off] : 0;
        __syncthreads();
        if (t < NPB) s_excl[t] += v;
        __syncthreads();
    }
    if (t < NPB) {
        int excl = s_excl[t] - s_hist[t];
        s_hist[t] = excl;  // becomes cursor
        int node = b * NPB + t;
        if (node < N_NODES) offsets[node] = base + excl;
    }
    __syncthreads();
    for (int i = t; i < nb; i += 256) {
        unsigned int u = s_e[i];
        int lp = atomicAdd(&s_hist[u & 127u], 1);
        sorted_src[base + lp] = (int)(u >> 7);
    }
    if (b == NB - 1 && t == 0) offsets[N_NODES] = N_EDGES;
}

// ---------------- dense: z = x @ W_l (fp16), r = x @ W_r + b (fp16) ----------------
template <typename XT>
__global__ __launch_bounds__(256) void dense_kernel(
        const XT* __restrict__ x,
        const float* __restrict__ wl, const float* __restrict__ wr,
        const float* __restrict__ bl,
        __half* __restrict__ z, __half* __restrict__ r, int n_nodes) {
    __shared__ float s_w[C][2 * C];
    __shared__ float s_x[64][C + 1];

    const int t = threadIdx.x;
    const int base = blockIdx.x * 64;

    for (int i = t; i < C * C; i += 256) {
        int k = i >> 6, c = i & 63;
        s_w[k][c] = wl[i];
        s_w[k][64 + c] = wr[i];
    }
    if constexpr (sizeof(XT) == 4) {
        for (int i = t; i < 1024; i += 256) {
            int n = i >> 4;
            int kq = i & 15;
            float4 v = make_float4(0.f, 0.f, 0.f, 0.f);
            if (base + n < n_nodes) v = ((const float4*)x)[((size_t)(base + n) << 4) + kq];
            s_x[n][kq * 4 + 0] = v.x;
            s_x[n][kq * 4 + 1] = v.y;
            s_x[n][kq * 4 + 2] = v.z;
            s_x[n][kq * 4 + 3] = v.w;
        }
    } else {
        for (int i = t; i < 2048; i += 256) {
            int n = i >> 5;
            int c2 = i & 31;
            float2 f = make_float2(0.f, 0.f);
            if (base + n < n_nodes)
                f = __half22float2(((const __half2*)x)[(size_t)(base + n) * 32 + c2]);
            s_x[n][2 * c2 + 0] = f.x;
            s_x[n][2 * c2 + 1] = f.y;
        }
    }
    __syncthreads();

    const int lane = t & 63;
    const int wv = t >> 6;
    const int cg = lane & 15;
    const int q = lane >> 4;
    const int n0 = wv * 16 + 4 * q;

    float4 bv = ((const float4*)bl)[cg];
    float accz[4][4];
    float accr[4][4];
#pragma unroll
    for (int i = 0; i < 4; ++i) {
        accz[i][0] = accz[i][1] = accz[i][2] = accz[i][3] = 0.f;
        accr[i][0] = bv.x; accr[i][1] = bv.y; accr[i][2] = bv.z; accr[i][3] = bv.w;
    }

#pragma unroll 8
    for (int k = 0; k < C; ++k) {
        float4 wlv = *(const float4*)&s_w[k][4 * cg];
        float4 wrv = *(const float4*)&s_w[k][64 + 4 * cg];
        float xk[4];
#pragma unroll
        for (int i = 0; i < 4; ++i) xk[i] = s_x[n0 + i][k];
#pragma unroll
        for (int i = 0; i < 4; ++i) {
            accz[i][0] += xk[i] * wlv.x;
            accz[i][1] += xk[i] * wlv.y;
            accz[i][2] += xk[i] * wlv.z;
            accz[i][3] += xk[i] * wlv.w;
            accr[i][0] += xk[i] * wrv.x;
            accr[i][1] += xk[i] * wrv.y;
            accr[i][2] += xk[i] * wrv.z;
            accr[i][3] += xk[i] * wrv.w;
        }
    }

#pragma unroll
    for (int i = 0; i < 4; ++i) {
        size_t gn = (size_t)base + n0 + i;
        if (gn < (size_t)n_nodes) {
            ((__half2*)z)[gn * 32 + 2 * cg + 0] = __float22half2_rn(make_float2(accz[i][0], accz[i][1]));
            ((__half2*)z)[gn * 32 + 2 * cg + 1] = __float22half2_rn(make_float2(accz[i][2], accz[i][3]));
            ((__half2*)r)[gn * 32 + 2 * cg + 0] = __float22half2_rn(make_float2(accr[i][0], accr[i][1]));
            ((__half2*)r)[gn * 32 + 2 * cg + 1] = __float22half2_rn(make_float2(accr[i][2], accr[i][3]));
        }
    }
}

// ---------------- gather: h = PReLU( mean_j z[nbr_j] + r ) ----------------
// Wave per node, lane = channel. 16 clamped row-loads in flight (no serial
// tail -- R10's tail loop killed MLP; clamp overhead is free at VALU<60%).
template <typename OT>
__global__ __launch_bounds__(256) void gather_kernel(
        const __half* __restrict__ z,
        const __half* __restrict__ r,
        const int* __restrict__ offsets,
        const int* __restrict__ sorted_src,
        const float* __restrict__ a,
        OT* __restrict__ out) {
    const int lane = threadIdx.x & 63;
    const int node = (blockIdx.x << 2) + (threadIdx.x >> 6);

    const int beg = offsets[node];
    const int deg = offsets[node + 1] - beg;
    const int last = deg - 1;

    float acc = 0.0f;
    for (int j = 0; j < deg; j += 16) {
        int idx[16];
#pragma unroll
        for (int i = 0; i < 16; ++i)
            idx[i] = sorted_src[beg + min(j + i, last)];
        float v[16];
#pragma unroll
        for (int i = 0; i < 16; ++i)
            v[i] = __half2float(z[(size_t)idx[i] * C + lane]);
        float sum = v[0];
#pragma unroll
        for (int i = 1; i < 16; ++i)
            sum += (j + i < deg) ? v[i] : 0.0f;
        acc += sum;
    }

    float rv = __half2float(r[(size_t)node * C + lane]);
    float h = acc / (float)max(deg, 1) + rv;
    float av = a[lane];
    float o = h >= 0.0f ? h : av * h;
    if constexpr (sizeof(OT) == 2)
        out[(size_t)node * C + lane] = __float2half(o);
    else
        out[(size_t)node * C + lane] = o;
}

extern "C" void kernel_launch(void* const* d_in, const int* in_sizes, int n_in,
                              void* d_out, int out_size, void* d_ws, size_t ws_size,
                              hipStream_t stream) {
    const float* x    = (const float*)d_in[0];
    const int*   ei   = (const int*)d_in[1];
    const float* w_l0 = (const float*)d_in[2];
    const float* b_l0 = (const float*)d_in[3];
    const float* w_r0 = (const float*)d_in[4];
    const float* a0   = (const float*)d_in[5];
    const float* w_l1 = (const float*)d_in[6];
    const float* b_l1 = (const float*)d_in[7];
    const float* w_r1 = (const float*)d_in[8];
    const float* a1   = (const float*)d_in[9];
    float* out = (float*)d_out;

    const int* src = ei;            // edge_index[0, :]
    const int* dst = ei + N_EDGES;  // edge_index[1, :]

    // ws: gcnt[1024] | offsets[N+1] | packed[NB*CAP] | sorted_src[E] | Z | R | H (fp16 N*C each)
    int* gcnt            = (int*)d_ws;
    int* offsets         = gcnt + 1024;
    unsigned int* packed = (unsigned int*)(offsets + (N_NODES + 1));
    int* sorted_src      = (int*)(packed + (size_t)NB * CAP);
    __half* Z            = (__half*)(sorted_src + N_EDGES);
    __half* R            = Z + (size_t)N_NODES * C;
    __half* H            = R + (size_t)N_NODES * C;

    hipMemsetAsync(gcnt, 0, 1024 * sizeof(int), stream);

    const int dblocks = (N_NODES + 63) / 64;
    const int nblocks = N_NODES / 4;  // exact

    partition_kernel<<<P1_BLOCKS, 256, 0, stream>>>(src, dst, gcnt, packed);
    sort_kernel<<<NB, 256, 0, stream>>>(packed, gcnt, offsets, sorted_src);

    // Layer 0: dense fp32->fp16, gather -> H (fp16)
    dense_kernel<float><<<dblocks, 256, 0, stream>>>(x, w_l0, w_r0, b_l0, Z, R, N_NODES);
    gather_kernel<__half><<<nblocks, 256, 0, stream>>>(Z, R, offsets, sorted_src, a0, H);

    // Layer 1: dense fp16->fp16, gather -> d_out (fp32)
    dense_kernel<__half><<<dblocks, 256, 0, stream>>>(H, w_l1, w_r1, b_l1, Z, R, N_NODES);
    gather_kernel<float><<<nblocks, 256, 0, stream>>>(Z, R, offsets, sorted_src, a1, out);
}